// Round 8
// baseline (234.794 us; speedup 1.0000x reference)
//
#include <hip/hip_runtime.h>
#include <stdint.h>

typedef unsigned short u16;
typedef __bf16 bf16x8 __attribute__((ext_vector_type(8)));
typedef float f32x4 __attribute__((ext_vector_type(4)));

#define N_NODES 50000
#define N_PAD   50048      // 391 * 128
#define NUM_E   800000
#define FDIM    256
#define NREL    8
#define NBASE   4
#define KBLK    5                      // 4 bases + self-loop
#define NKSTEP  20                     // KBLK * 4 (BK=64)
#define NSEG    N_NODES                // dst-only segments
#define NBLK    49                     // ceil(NSEG/1024)
#define MTILES  196                    // ceil(N_PAD/256)

// prep kernel block ranges
#define PREP_FEAT_BLOCKS 12512         // N_PAD*64/256
#define PREP_WT_BLOCKS   1280          // 5*65536/256
#define PREP_ZERO_BLOCKS 196           // ceil(NSEG/256)

__device__ __forceinline__ u16 f2bf(float f) {
  uint32_t u = __float_as_uint(f);
  u += 0x7FFFu + ((u >> 16) & 1u);   // RNE
  return (u16)(u >> 16);
}
__device__ __forceinline__ float bf2f(u16 h) {
  return __uint_as_float(((uint32_t)h) << 16);
}

// async global->LDS, 16B per lane; LDS dest = wave-uniform base + lane*16
__device__ __forceinline__ void gload_lds16(const void* g, void* l) {
  __builtin_amdgcn_global_load_lds(
      (__attribute__((address_space(1))) uint32_t*)(void*)(uintptr_t)g,
      (__attribute__((address_space(3))) uint32_t*)(uintptr_t)l,
      16, 0, 0);
}

// ---- fused prep: feat f32->bf16 (zero-pad), Wb transpose, zero counts ----
// Wb_all[b][o][i] = weight[b][i][o] (b<4);  Wb_all[4][o][i] = loop_w[i][o]
__global__ __launch_bounds__(256) void prep_k(const float* __restrict__ feat,
                                              const float* __restrict__ weight,
                                              const float* __restrict__ loop_w,
                                              u16* __restrict__ fb,
                                              u16* __restrict__ Wb_all,
                                              int* __restrict__ cnt) {
  const int b = blockIdx.x;
  const int tid = threadIdx.x;
  if (b < PREP_FEAT_BLOCKS) {
    int idx = b * 256 + tid;                      // one thread = 4 elems
    int row = idx >> 6;
    int q = (idx & 63) * 4;
    float4 v = make_float4(0.f, 0.f, 0.f, 0.f);
    if (row < N_NODES) v = *reinterpret_cast<const float4*>(feat + (size_t)row * FDIM + q);
    ushort4 h;
    h.x = f2bf(v.x); h.y = f2bf(v.y); h.z = f2bf(v.z); h.w = f2bf(v.w);
    *reinterpret_cast<ushort4*>(fb + (size_t)row * FDIM + q) = h;
  } else if (b < PREP_FEAT_BLOCKS + PREP_WT_BLOCKS) {
    int idx = (b - PREP_FEAT_BLOCKS) * 256 + tid;
    int r = idx >> 16, rem = idx & 65535;
    int o = rem >> 8, i = rem & 255;
    float s = (r < NBASE) ? weight[(size_t)r * 65536 + i * 256 + o]
                          : loop_w[i * 256 + o];
    Wb_all[idx] = f2bf(s);
  } else {
    int i = (b - PREP_FEAT_BLOCKS - PREP_WT_BLOCKS) * 256 + tid;
    if (i < NSEG) cnt[i] = 0;
  }
}

// ---- CSR build over dst ----
__global__ __launch_bounds__(256) void hist_k(const int* __restrict__ dst,
                                              int* __restrict__ cnt) {
  int e = blockIdx.x * 256 + threadIdx.x;
  if (e < NUM_E) atomicAdd(&cnt[dst[e]], 1);
}

// block-level scan (1024/block): rowstart[i] = in-block exclusive prefix
__global__ __launch_bounds__(1024) void scan1(const int* __restrict__ cnt,
                                              int* __restrict__ rowstart,
                                              int* __restrict__ blocksum) {
  __shared__ int wtot[16], woff[16];
  const int tid = threadIdx.x, lane = tid & 63, w = tid >> 6;
  const int i = blockIdx.x * 1024 + tid;
  const int v = (i < NSEG) ? cnt[i] : 0;
  int inc = v;
#pragma unroll
  for (int off = 1; off < 64; off <<= 1) {
    int t = __shfl_up(inc, off);
    if (lane >= off) inc += t;
  }
  if (lane == 63) wtot[w] = inc;
  __syncthreads();
  if (w == 0) {
    int tv = (lane < 16) ? wtot[lane] : 0;
    int tinc = tv;
#pragma unroll
    for (int off = 1; off < 16; off <<= 1) {
      int t = __shfl_up(tinc, off);
      if (lane >= off) tinc += t;
    }
    if (lane < 16) woff[lane] = tinc - tv;
    if (lane == 15) blocksum[blockIdx.x] = tinc;
  }
  __syncthreads();
  if (i < NSEG) rowstart[i] = inc - v + woff[w];
}

// exclusive scan of the block sums (single block)
__global__ __launch_bounds__(512) void scan2(int* __restrict__ blocksum) {
  __shared__ int s[512];
  const int tid = threadIdx.x;
  const int v = (tid < NBLK) ? blocksum[tid] : 0;
  s[tid] = v;
#pragma unroll
  for (int off = 1; off < 512; off <<= 1) {
    __syncthreads();
    int t = (tid >= off) ? s[tid - off] : 0;
    __syncthreads();
    s[tid] += t;
  }
  if (tid < NBLK) blocksum[tid] = s[tid] - v;
}

// add block offsets in place; init cursor; terminator
__global__ __launch_bounds__(1024) void scan3(int* __restrict__ rowstart,
                                              const int* __restrict__ blockoff,
                                              int* __restrict__ cursor) {
  const int i = blockIdx.x * 1024 + threadIdx.x;
  if (i < NSEG) {
    const int v = rowstart[i] + blockoff[i >> 10];
    rowstart[i] = v;
    cursor[i] = v;
  }
  if (i == NSEG) rowstart[NSEG] = NUM_E;
}

// bucket edges into CSR order: key = src*8 + etype, plus norm
__global__ __launch_bounds__(256) void bucket_k(const int* __restrict__ src,
                                                const int* __restrict__ dst,
                                                const int* __restrict__ et,
                                                const float* __restrict__ norm,
                                                int* __restrict__ cursor,
                                                int* __restrict__ keys,
                                                float* __restrict__ norms) {
  int e = blockIdx.x * 256 + threadIdx.x;
  if (e >= NUM_E) return;
  const int pos = atomicAdd(&cursor[dst[e]], 1);
  keys[pos]  = src[e] * NREL + et[e];
  norms[pos] = norm[e];
}

// ---- aggregate into base channels:
//      G[d][b][:] = sum_{e->d} norm_e * w_comp[et_e][b] * feat[src_e][:]
//      one wave per dst node; DEPTH-4 software-pipelined gathers (4x MLP) ----
__global__ __launch_bounds__(256) void agg_G(const u16* __restrict__ feat_bf,
                                             const int* __restrict__ rowstart,
                                             const int* __restrict__ keys,
                                             const float* __restrict__ norms,
                                             const float* __restrict__ w_comp,
                                             u16* __restrict__ G) {
  __shared__ float4 wcs4[NREL];
  if (threadIdx.x < NREL) {
    const float* wr = w_comp + threadIdx.x * NBASE;
    wcs4[threadIdx.x] = make_float4(wr[0], wr[1], wr[2], wr[3]);
  }
  __syncthreads();
  const int n = blockIdx.x * 4 + (threadIdx.x >> 6);   // grid exact: n < N_NODES
  const int lane = threadIdx.x & 63;
  const int beg = rowstart[n], end = rowstart[n + 1];

  f32x4 acc0 = {}, acc1 = {}, acc2 = {}, acc3 = {};

  for (int base = beg; base < end; base += 64) {
    const int m = min(64, end - base);                 // wave-uniform
    int kv = 0; float nv = 0.f;
    if (lane < m) { kv = keys[base + lane]; nv = norms[base + lane]; }

    // fetch edge j's (key, coeff-scale, feat row); j >= m -> zero coeff, row 0
    auto fetch = [&](int j, int& k, float& nm, ushort4& h) {
      const int jc = (j < m) ? j : 0;                  // clamp: valid lane idx
      k = __shfl(kv, jc);
      nm = (j < m) ? __shfl(nv, jc) : 0.f;
      h = *reinterpret_cast<const ushort4*>(
          feat_bf + (size_t)(k >> 3) * FDIM + lane * 4);
    };
    auto body = [&](int k, float nm, ushort4 h) {
      const float4 w = wcs4[k & 7];                    // one b128 broadcast
      const float c0 = nm * w.x, c1 = nm * w.y, c2 = nm * w.z, c3 = nm * w.w;
      const float f0 = bf2f(h.x), f1 = bf2f(h.y), f2 = bf2f(h.z), f3 = bf2f(h.w);
      acc0[0] += f0 * c0; acc0[1] += f1 * c0; acc0[2] += f2 * c0; acc0[3] += f3 * c0;
      acc1[0] += f0 * c1; acc1[1] += f1 * c1; acc1[2] += f2 * c1; acc1[3] += f3 * c1;
      acc2[0] += f0 * c2; acc2[1] += f1 * c2; acc2[2] += f2 * c2; acc2[3] += f3 * c2;
      acc3[0] += f0 * c3; acc3[1] += f1 * c3; acc3[2] += f2 * c3; acc3[3] += f3 * c3;
    };

    ushort4 hA, hB, hC, hD;
    int kA, kB, kC, kD;
    float nA, nB, nC, nD;
    fetch(0, kA, nA, hA);
    fetch(1, kB, nB, hB);
    fetch(2, kC, nC, hC);
    fetch(3, kD, nD, hD);

    for (int j0 = 0; j0 < m; j0 += 4) {
      const bool more = (j0 + 4) < m;
      ushort4 pA, pB, pC, pD;
      int qA, qB, qC, qD;
      float mA, mB, mC, mD;
      if (more) {                     // prefetch next chunk (hidden under FMAs)
        fetch(j0 + 4, qA, mA, pA);
        fetch(j0 + 5, qB, mB, pB);
        fetch(j0 + 6, qC, mC, pC);
        fetch(j0 + 7, qD, mD, pD);
      }
      body(kA, nA, hA);
      body(kB, nB, hB);
      body(kC, nC, hC);
      body(kD, nD, hD);
      if (more) {
        kA = qA; nA = mA; hA = pA;
        kB = qB; nB = mB; hB = pB;
        kC = qC; nC = mC; hC = pC;
        kD = qD; nD = mD; hD = pD;
      }
    }
  }

  const size_t gbase = (size_t)n * (NBASE * FDIM) + lane * 4;
  ushort4 hh;
  hh.x = f2bf(acc0[0]); hh.y = f2bf(acc0[1]); hh.z = f2bf(acc0[2]); hh.w = f2bf(acc0[3]);
  *reinterpret_cast<ushort4*>(G + gbase + 0 * FDIM) = hh;
  hh.x = f2bf(acc1[0]); hh.y = f2bf(acc1[1]); hh.z = f2bf(acc1[2]); hh.w = f2bf(acc1[3]);
  *reinterpret_cast<ushort4*>(G + gbase + 1 * FDIM) = hh;
  hh.x = f2bf(acc2[0]); hh.y = f2bf(acc2[1]); hh.z = f2bf(acc2[2]); hh.w = f2bf(acc2[3]);
  *reinterpret_cast<ushort4*>(G + gbase + 2 * FDIM) = hh;
  hh.x = f2bf(acc3[0]); hh.y = f2bf(acc3[1]); hh.z = f2bf(acc3[2]); hh.w = f2bf(acc3[3]);
  *reinterpret_cast<ushort4*>(G + gbase + 3 * FDIM) = hh;
}

// ---- fused GEMM: out[m][o] = relu( sum_{b<4} G[m][b][:]@V_b + feat[m]@lw + bias )
//      BM=256, BN=256, BK=64, K=1280 (20 steps), 8 waves (2Mx4N), wave tile 128x64.
//      Double-buffered LDS, stage-early, both-sides XOR swizzle (verified r6: 0 conflicts). ----
__global__ __launch_bounds__(512, 2) void fused_gemm(const u16* __restrict__ G,
                                                     const u16* __restrict__ feat_bf,
                                                     const u16* __restrict__ Wb_all,
                                                     const float* __restrict__ bias,
                                                     float* __restrict__ out) {
  __shared__ __align__(16) u16 As[2][256 * 64];   // 2 x 32 KB
  __shared__ __align__(16) u16 Bs[2][256 * 64];   // 2 x 32 KB
  const int tid = threadIdx.x;
  const int lane = tid & 63;
  const int w = tid >> 6;          // 0..7
  const int wm = w >> 2, wn = w & 3;
  const int mtile = blockIdx.x;

  // per-thread staging constants (source pre-swizzle)
  const int srow = tid >> 3;                      // 0..63: row within 64-row group
  const int scolx = ((tid & 7) << 3) ^ ((srow & 7) << 3);  // swizzled elem col

  f32x4 acc[8][4] = {};

  // stage K-step ks into buffer buf: A 256x64 from G/feat, B 256x64 from Wb_all
  auto stage = [&](int ks, int buf) {
    const int r = ks >> 2, kk4 = ks & 3;
    const int kcol = kk4 * 64 + scolx;
#pragma unroll
    for (int q = 0; q < 4; ++q) {
      const int arow = q * 64 + srow;             // 0..255 within tile
      int gr = mtile * 256 + arow;
      if (gr >= N_PAD) gr = N_PAD - 1;            // clamp (garbage rows discarded)
      const u16* asrc = (r < NBASE)
          ? G + (size_t)gr * 1024 + r * 256 + kcol
          : feat_bf + (size_t)gr * 256 + kcol;
      gload_lds16(asrc, &As[buf][q * 4096 + tid * 8]);
      const u16* bsrc = Wb_all + (size_t)r * 65536 + (size_t)arow * 256 + kcol;
      gload_lds16(bsrc, &Bs[buf][q * 4096 + tid * 8]);
    }
  };

  stage(0, 0);
  __syncthreads();
  for (int t = 0; t < NKSTEP; ++t) {
    const int cur = t & 1;
    if (t + 1 < NKSTEP) stage(t + 1, cur ^ 1);    // flight hidden under compute
#pragma unroll
    for (int kk = 0; kk < 2; ++kk) {
      const int colx = (kk * 32 + ((lane >> 4) << 3)) ^ ((lane & 7) << 3);
      bf16x8 a[8], b[4];
#pragma unroll
      for (int mf = 0; mf < 8; ++mf)
        a[mf] = *reinterpret_cast<const bf16x8*>(
            &As[cur][(wm * 128 + mf * 16 + (lane & 15)) * 64 + colx]);
#pragma unroll
      for (int nf = 0; nf < 4; ++nf)
        b[nf] = *reinterpret_cast<const bf16x8*>(
            &Bs[cur][(wn * 64 + nf * 16 + (lane & 15)) * 64 + colx]);
      __builtin_amdgcn_s_setprio(1);
#pragma unroll
      for (int mf = 0; mf < 8; ++mf)
#pragma unroll
        for (int nf = 0; nf < 4; ++nf)
          acc[mf][nf] = __builtin_amdgcn_mfma_f32_16x16x32_bf16(b[nf], a[mf], acc[mf][nf], 0, 0, 0);
      __builtin_amdgcn_s_setprio(0);
    }
    __syncthreads();                              // drains stage + read-protect
  }

  // epilogue: out = relu(acc + bias); D col(lane&15)=m, o lane-sequential
#pragma unroll
  for (int mf = 0; mf < 8; ++mf) {
    const int m = mtile * 256 + wm * 128 + mf * 16 + (lane & 15);
    if (m >= N_NODES) continue;
#pragma unroll
    for (int nf = 0; nf < 4; ++nf) {
      const int o0 = wn * 64 + nf * 16 + ((lane >> 4) << 2);
      const float4 bv = *reinterpret_cast<const float4*>(bias + o0);
      float4 v;
      v.x = fmaxf(acc[mf][nf][0] + bv.x, 0.f);
      v.y = fmaxf(acc[mf][nf][1] + bv.y, 0.f);
      v.z = fmaxf(acc[mf][nf][2] + bv.z, 0.f);
      v.w = fmaxf(acc[mf][nf][3] + bv.w, 0.f);
      *reinterpret_cast<float4*>(out + (size_t)m * 256 + o0) = v;
    }
  }
}

extern "C" void kernel_launch(void* const* d_in, const int* in_sizes, int n_in,
                              void* d_out, int out_size, void* d_ws, size_t ws_size,
                              hipStream_t stream) {
  (void)in_sizes; (void)n_in; (void)out_size; (void)ws_size;
  const float* feat   = (const float*)d_in[0];
  const float* weight = (const float*)d_in[1];
  const float* w_comp = (const float*)d_in[2];
  const float* loop_w = (const float*)d_in[3];
  const float* h_bias = (const float*)d_in[4];
  const float* norm   = (const float*)d_in[5];
  const int*   src    = (const int*)d_in[6];
  const int*   dst    = (const int*)d_in[7];
  const int*   et     = (const int*)d_in[8];
  float* out = (float*)d_out;

  char* ws = (char*)d_ws;
  u16*   feat_bf  = (u16*)(ws);                      // 25,624,576
  u16*   Wb_all   = (u16*)(ws + 25624576);           //    655,360
  u16*   G        = (u16*)(ws + 26279936);           // 102,498,304 (N_PAD*1024*2)
  int*   counts   = (int*)(ws + 128778240);          //    200,192
  int*   rowstart = (int*)(ws + 128978432);          //    200,448 (NSEG+1, padded)
  int*   cursor   = (int*)(ws + 129178880);          //    200,192
  int*   keys     = (int*)(ws + 129379072);          //  3,200,000
  float* norms    = (float*)(ws + 132579072);        //  3,200,000
  int*   blocksum = (int*)(ws + 135779072);          //        256

  // fused prep: feat->bf16, Wb transpose, zero counts
  prep_k<<<PREP_FEAT_BLOCKS + PREP_WT_BLOCKS + PREP_ZERO_BLOCKS, 256, 0, stream>>>(
      feat, weight, loop_w, feat_bf, Wb_all, counts);

  // CSR build over dst
  hist_k<<<(NUM_E + 255) / 256, 256, 0, stream>>>(dst, counts);
  scan1<<<NBLK, 1024, 0, stream>>>(counts, rowstart, blocksum);
  scan2<<<1, 512, 0, stream>>>(blocksum);
  scan3<<<NBLK + 1, 1024, 0, stream>>>(rowstart, blocksum, cursor);
  bucket_k<<<(NUM_E + 255) / 256, 256, 0, stream>>>(src, dst, et, norm, cursor, keys, norms);

  // aggregate into 4 base channels (1 wave/node; depth-4 gather pipeline)
  agg_G<<<N_NODES / 4, 256, 0, stream>>>(feat_bf, rowstart, keys, norms, w_comp, G);

  // one fused GEMM: K = 4 bases + self-loop; bias + relu fused
  fused_gemm<<<MTILES, 512, 0, stream>>>(G, feat_bf, Wb_all, h_bias, out);
}

// Round 9
// 229.897 us; speedup vs baseline: 1.0213x; 1.0213x over previous
//
#include <hip/hip_runtime.h>
#include <stdint.h>

typedef unsigned short u16;
typedef __bf16 bf16x8 __attribute__((ext_vector_type(8)));
typedef float f32x4 __attribute__((ext_vector_type(4)));

#define N_NODES 50000
#define N_PAD   50048      // 391 * 128
#define NUM_E   800000
#define FDIM    256
#define NREL    8
#define NBASE   4
#define KBLK    5                      // 4 bases + self-loop
#define NKSTEP  20                     // KBLK * 4 (BK=64)
#define NSEG    N_NODES                // dst-only segments
#define NBLK    49                     // ceil(NSEG/1024)
#define MTILES  196                    // ceil(N_PAD/256)

// prep kernel block ranges
#define PREP_FEAT_BLOCKS 12512         // N_PAD*64/256
#define PREP_WT_BLOCKS   1280          // 5*65536/256
#define PREP_ZERO_BLOCKS 196           // ceil(NSEG/256)

__device__ __forceinline__ u16 f2bf(float f) {
  uint32_t u = __float_as_uint(f);
  u += 0x7FFFu + ((u >> 16) & 1u);   // RNE
  return (u16)(u >> 16);
}
__device__ __forceinline__ float bf2f(u16 h) {
  return __uint_as_float(((uint32_t)h) << 16);
}

// async global->LDS, 16B per lane; LDS dest = wave-uniform base + lane*16
__device__ __forceinline__ void gload_lds16(const void* g, void* l) {
  __builtin_amdgcn_global_load_lds(
      (__attribute__((address_space(1))) uint32_t*)(void*)(uintptr_t)g,
      (__attribute__((address_space(3))) uint32_t*)(uintptr_t)l,
      16, 0, 0);
}

// ---- fused prep: feat f32->bf16 (zero-pad), Wb transpose, zero counts ----
// Wb_all[b][o][i] = weight[b][i][o] (b<4);  Wb_all[4][o][i] = loop_w[i][o]
__global__ __launch_bounds__(256) void prep_k(const float* __restrict__ feat,
                                              const float* __restrict__ weight,
                                              const float* __restrict__ loop_w,
                                              u16* __restrict__ fb,
                                              u16* __restrict__ Wb_all,
                                              int* __restrict__ cnt) {
  const int b = blockIdx.x;
  const int tid = threadIdx.x;
  if (b < PREP_FEAT_BLOCKS) {
    int idx = b * 256 + tid;                      // one thread = 4 elems
    int row = idx >> 6;
    int q = (idx & 63) * 4;
    float4 v = make_float4(0.f, 0.f, 0.f, 0.f);
    if (row < N_NODES) v = *reinterpret_cast<const float4*>(feat + (size_t)row * FDIM + q);
    ushort4 h;
    h.x = f2bf(v.x); h.y = f2bf(v.y); h.z = f2bf(v.z); h.w = f2bf(v.w);
    *reinterpret_cast<ushort4*>(fb + (size_t)row * FDIM + q) = h;
  } else if (b < PREP_FEAT_BLOCKS + PREP_WT_BLOCKS) {
    int idx = (b - PREP_FEAT_BLOCKS) * 256 + tid;
    int r = idx >> 16, rem = idx & 65535;
    int o = rem >> 8, i = rem & 255;
    float s = (r < NBASE) ? weight[(size_t)r * 65536 + i * 256 + o]
                          : loop_w[i * 256 + o];
    Wb_all[idx] = f2bf(s);
  } else {
    int i = (b - PREP_FEAT_BLOCKS - PREP_WT_BLOCKS) * 256 + tid;
    if (i < NSEG) cnt[i] = 0;
  }
}

// ---- CSR build over dst ----
__global__ __launch_bounds__(256) void hist_k(const int* __restrict__ dst,
                                              int* __restrict__ cnt) {
  int e = blockIdx.x * 256 + threadIdx.x;
  if (e < NUM_E) atomicAdd(&cnt[dst[e]], 1);
}

// block-level scan (1024/block): rowstart[i] = in-block exclusive prefix
__global__ __launch_bounds__(1024) void scan1(const int* __restrict__ cnt,
                                              int* __restrict__ rowstart,
                                              int* __restrict__ blocksum) {
  __shared__ int wtot[16], woff[16];
  const int tid = threadIdx.x, lane = tid & 63, w = tid >> 6;
  const int i = blockIdx.x * 1024 + tid;
  const int v = (i < NSEG) ? cnt[i] : 0;
  int inc = v;
#pragma unroll
  for (int off = 1; off < 64; off <<= 1) {
    int t = __shfl_up(inc, off);
    if (lane >= off) inc += t;
  }
  if (lane == 63) wtot[w] = inc;
  __syncthreads();
  if (w == 0) {
    int tv = (lane < 16) ? wtot[lane] : 0;
    int tinc = tv;
#pragma unroll
    for (int off = 1; off < 16; off <<= 1) {
      int t = __shfl_up(tinc, off);
      if (lane >= off) tinc += t;
    }
    if (lane < 16) woff[lane] = tinc - tv;
    if (lane == 15) blocksum[blockIdx.x] = tinc;
  }
  __syncthreads();
  if (i < NSEG) rowstart[i] = inc - v + woff[w];
}

// exclusive scan of the block sums (single block)
__global__ __launch_bounds__(512) void scan2(int* __restrict__ blocksum) {
  __shared__ int s[512];
  const int tid = threadIdx.x;
  const int v = (tid < NBLK) ? blocksum[tid] : 0;
  s[tid] = v;
#pragma unroll
  for (int off = 1; off < 512; off <<= 1) {
    __syncthreads();
    int t = (tid >= off) ? s[tid - off] : 0;
    __syncthreads();
    s[tid] += t;
  }
  if (tid < NBLK) blocksum[tid] = s[tid] - v;
}

// add block offsets in place; init cursor; terminator
__global__ __launch_bounds__(1024) void scan3(int* __restrict__ rowstart,
                                              const int* __restrict__ blockoff,
                                              int* __restrict__ cursor) {
  const int i = blockIdx.x * 1024 + threadIdx.x;
  if (i < NSEG) {
    const int v = rowstart[i] + blockoff[i >> 10];
    rowstart[i] = v;
    cursor[i] = v;
  }
  if (i == NSEG) rowstart[NSEG] = NUM_E;
}

// bucket edges into CSR order: one int2 per edge {src*8+etype, norm bits}
__global__ __launch_bounds__(256) void bucket_k(const int* __restrict__ src,
                                                const int* __restrict__ dst,
                                                const int* __restrict__ et,
                                                const float* __restrict__ norm,
                                                int* __restrict__ cursor,
                                                int2* __restrict__ ekv) {
  int e = blockIdx.x * 256 + threadIdx.x;
  if (e >= NUM_E) return;
  const int pos = atomicAdd(&cursor[dst[e]], 1);
  int2 kv;
  kv.x = src[e] * NREL + et[e];
  kv.y = __float_as_int(norm[e]);
  ekv[pos] = kv;
}

// ---- aggregate into per-relation sums then combine into 4 base channels:
//      A_r[d][:] = sum_{e->d, et=r} norm_e * feat[src_e][:]
//      G[d][b][:] = sum_r w_comp[r][b] * A_r[d][:]
//      one wave per dst node; groups of 8 edges, scalar (readlane) edge
//      descriptors, 8 gathers in flight, wave-uniform switch on etype ----
__global__ __launch_bounds__(256) void agg_G(const u16* __restrict__ feat_bf,
                                             const int* __restrict__ rowstart,
                                             const int2* __restrict__ ekv,
                                             const float* __restrict__ w_comp,
                                             u16* __restrict__ G) {
  __shared__ float4 wcs4[NREL];
  if (threadIdx.x < NREL) {
    const float* wr = w_comp + threadIdx.x * NBASE;
    wcs4[threadIdx.x] = make_float4(wr[0], wr[1], wr[2], wr[3]);
  }
  __syncthreads();
  const int n = blockIdx.x * 4 + (threadIdx.x >> 6);   // grid exact: n < N_NODES
  const int lane = threadIdx.x & 63;
  const int beg = rowstart[n], end = rowstart[n + 1];

  f32x4 a0 = {}, a1 = {}, a2 = {}, a3 = {}, a4 = {}, a5 = {}, a6 = {}, a7 = {};
  const u16* fl = feat_bf + lane * 4;

  for (int base = beg; base < end; base += 64) {
    const int m = min(64, end - base);                 // wave-uniform
    int kvi = 0, nvi = 0;
    if (lane < m) {
      const int2 e = ekv[base + lane];
      kvi = e.x; nvi = e.y;                            // pad lanes: key 0, norm 0
    }
#pragma unroll
    for (int g = 0; g < 8; ++g) {
      if (g * 8 >= m) break;                           // wave-uniform exit
      ushort4 h[8];
      int ks[8]; float ns[8];
#pragma unroll
      for (int jj = 0; jj < 8; ++jj) {
        const int j = g * 8 + jj;                      // compile-time lane index
        ks[jj] = __builtin_amdgcn_readlane(kvi, j);    // SGPR
        ns[jj] = __uint_as_float((unsigned)__builtin_amdgcn_readlane(nvi, j));
        h[jj] = *reinterpret_cast<const ushort4*>(
            fl + ((size_t)((unsigned)ks[jj] >> 3) << 8));   // saddr + lane*8B
      }
#pragma unroll
      for (int jj = 0; jj < 8; ++jj) {
        const float nm = ns[jj];                       // 0 for pad edges
        const float f0 = bf2f(h[jj].x), f1 = bf2f(h[jj].y),
                    f2 = bf2f(h[jj].z), f3 = bf2f(h[jj].w);
        switch (ks[jj] & 7) {                          // scalar branch tree
          case 0: a0[0]+=f0*nm; a0[1]+=f1*nm; a0[2]+=f2*nm; a0[3]+=f3*nm; break;
          case 1: a1[0]+=f0*nm; a1[1]+=f1*nm; a1[2]+=f2*nm; a1[3]+=f3*nm; break;
          case 2: a2[0]+=f0*nm; a2[1]+=f1*nm; a2[2]+=f2*nm; a2[3]+=f3*nm; break;
          case 3: a3[0]+=f0*nm; a3[1]+=f1*nm; a3[2]+=f2*nm; a3[3]+=f3*nm; break;
          case 4: a4[0]+=f0*nm; a4[1]+=f1*nm; a4[2]+=f2*nm; a4[3]+=f3*nm; break;
          case 5: a5[0]+=f0*nm; a5[1]+=f1*nm; a5[2]+=f2*nm; a5[3]+=f3*nm; break;
          case 6: a6[0]+=f0*nm; a6[1]+=f1*nm; a6[2]+=f2*nm; a6[3]+=f3*nm; break;
          default: a7[0]+=f0*nm; a7[1]+=f1*nm; a7[2]+=f2*nm; a7[3]+=f3*nm; break;
        }
      }
    }
  }

  // combine per-relation sums into base channels: c_b += w_comp[r][b] * A_r
  f32x4 c0 = {}, c1 = {}, c2 = {}, c3 = {};
#define COMB(AR, R) { const float4 w = wcs4[R];                          \
    c0[0]+=w.x*AR[0]; c0[1]+=w.x*AR[1]; c0[2]+=w.x*AR[2]; c0[3]+=w.x*AR[3]; \
    c1[0]+=w.y*AR[0]; c1[1]+=w.y*AR[1]; c1[2]+=w.y*AR[2]; c1[3]+=w.y*AR[3]; \
    c2[0]+=w.z*AR[0]; c2[1]+=w.z*AR[1]; c2[2]+=w.z*AR[2]; c2[3]+=w.z*AR[3]; \
    c3[0]+=w.w*AR[0]; c3[1]+=w.w*AR[1]; c3[2]+=w.w*AR[2]; c3[3]+=w.w*AR[3]; }
  COMB(a0, 0) COMB(a1, 1) COMB(a2, 2) COMB(a3, 3)
  COMB(a4, 4) COMB(a5, 5) COMB(a6, 6) COMB(a7, 7)
#undef COMB

  const size_t gbase = (size_t)n * (NBASE * FDIM) + lane * 4;
  ushort4 hh;
  hh.x = f2bf(c0[0]); hh.y = f2bf(c0[1]); hh.z = f2bf(c0[2]); hh.w = f2bf(c0[3]);
  *reinterpret_cast<ushort4*>(G + gbase + 0 * FDIM) = hh;
  hh.x = f2bf(c1[0]); hh.y = f2bf(c1[1]); hh.z = f2bf(c1[2]); hh.w = f2bf(c1[3]);
  *reinterpret_cast<ushort4*>(G + gbase + 1 * FDIM) = hh;
  hh.x = f2bf(c2[0]); hh.y = f2bf(c2[1]); hh.z = f2bf(c2[2]); hh.w = f2bf(c2[3]);
  *reinterpret_cast<ushort4*>(G + gbase + 2 * FDIM) = hh;
  hh.x = f2bf(c3[0]); hh.y = f2bf(c3[1]); hh.z = f2bf(c3[2]); hh.w = f2bf(c3[3]);
  *reinterpret_cast<ushort4*>(G + gbase + 3 * FDIM) = hh;
}

// ---- fused GEMM: out[m][o] = relu( sum_{b<4} G[m][b][:]@V_b + feat[m]@lw + bias )
//      BM=256, BN=256, BK=64, K=1280 (20 steps), 8 waves (2Mx4N), wave tile 128x64.
//      Double-buffered LDS, stage-early, both-sides XOR swizzle (verified r6: 0 conflicts). ----
__global__ __launch_bounds__(512, 2) void fused_gemm(const u16* __restrict__ G,
                                                     const u16* __restrict__ feat_bf,
                                                     const u16* __restrict__ Wb_all,
                                                     const float* __restrict__ bias,
                                                     float* __restrict__ out) {
  __shared__ __align__(16) u16 As[2][256 * 64];   // 2 x 32 KB
  __shared__ __align__(16) u16 Bs[2][256 * 64];   // 2 x 32 KB
  const int tid = threadIdx.x;
  const int lane = tid & 63;
  const int w = tid >> 6;          // 0..7
  const int wm = w >> 2, wn = w & 3;
  const int mtile = blockIdx.x;

  // per-thread staging constants (source pre-swizzle)
  const int srow = tid >> 3;                      // 0..63: row within 64-row group
  const int scolx = ((tid & 7) << 3) ^ ((srow & 7) << 3);  // swizzled elem col

  f32x4 acc[8][4] = {};

  // stage K-step ks into buffer buf: A 256x64 from G/feat, B 256x64 from Wb_all
  auto stage = [&](int ks, int buf) {
    const int r = ks >> 2, kk4 = ks & 3;
    const int kcol = kk4 * 64 + scolx;
#pragma unroll
    for (int q = 0; q < 4; ++q) {
      const int arow = q * 64 + srow;             // 0..255 within tile
      int gr = mtile * 256 + arow;
      if (gr >= N_PAD) gr = N_PAD - 1;            // clamp (garbage rows discarded)
      const u16* asrc = (r < NBASE)
          ? G + (size_t)gr * 1024 + r * 256 + kcol
          : feat_bf + (size_t)gr * 256 + kcol;
      gload_lds16(asrc, &As[buf][q * 4096 + tid * 8]);
      const u16* bsrc = Wb_all + (size_t)r * 65536 + (size_t)arow * 256 + kcol;
      gload_lds16(bsrc, &Bs[buf][q * 4096 + tid * 8]);
    }
  };

  stage(0, 0);
  __syncthreads();
  for (int t = 0; t < NKSTEP; ++t) {
    const int cur = t & 1;
    if (t + 1 < NKSTEP) stage(t + 1, cur ^ 1);    // flight hidden under compute
#pragma unroll
    for (int kk = 0; kk < 2; ++kk) {
      const int colx = (kk * 32 + ((lane >> 4) << 3)) ^ ((lane & 7) << 3);
      bf16x8 a[8], b[4];
#pragma unroll
      for (int mf = 0; mf < 8; ++mf)
        a[mf] = *reinterpret_cast<const bf16x8*>(
            &As[cur][(wm * 128 + mf * 16 + (lane & 15)) * 64 + colx]);
#pragma unroll
      for (int nf = 0; nf < 4; ++nf)
        b[nf] = *reinterpret_cast<const bf16x8*>(
            &Bs[cur][(wn * 64 + nf * 16 + (lane & 15)) * 64 + colx]);
      __builtin_amdgcn_s_setprio(1);
#pragma unroll
      for (int mf = 0; mf < 8; ++mf)
#pragma unroll
        for (int nf = 0; nf < 4; ++nf)
          acc[mf][nf] = __builtin_amdgcn_mfma_f32_16x16x32_bf16(b[nf], a[mf], acc[mf][nf], 0, 0, 0);
      __builtin_amdgcn_s_setprio(0);
    }
    __syncthreads();                              // drains stage + read-protect
  }

  // epilogue: out = relu(acc + bias); D col(lane&15)=m, o lane-sequential
#pragma unroll
  for (int mf = 0; mf < 8; ++mf) {
    const int m = mtile * 256 + wm * 128 + mf * 16 + (lane & 15);
    if (m >= N_NODES) continue;
#pragma unroll
    for (int nf = 0; nf < 4; ++nf) {
      const int o0 = wn * 64 + nf * 16 + ((lane >> 4) << 2);
      const float4 bv = *reinterpret_cast<const float4*>(bias + o0);
      float4 v;
      v.x = fmaxf(acc[mf][nf][0] + bv.x, 0.f);
      v.y = fmaxf(acc[mf][nf][1] + bv.y, 0.f);
      v.z = fmaxf(acc[mf][nf][2] + bv.z, 0.f);
      v.w = fmaxf(acc[mf][nf][3] + bv.w, 0.f);
      *reinterpret_cast<float4*>(out + (size_t)m * 256 + o0) = v;
    }
  }
}

extern "C" void kernel_launch(void* const* d_in, const int* in_sizes, int n_in,
                              void* d_out, int out_size, void* d_ws, size_t ws_size,
                              hipStream_t stream) {
  (void)in_sizes; (void)n_in; (void)out_size; (void)ws_size;
  const float* feat   = (const float*)d_in[0];
  const float* weight = (const float*)d_in[1];
  const float* w_comp = (const float*)d_in[2];
  const float* loop_w = (const float*)d_in[3];
  const float* h_bias = (const float*)d_in[4];
  const float* norm   = (const float*)d_in[5];
  const int*   src    = (const int*)d_in[6];
  const int*   dst    = (const int*)d_in[7];
  const int*   et     = (const int*)d_in[8];
  float* out = (float*)d_out;

  char* ws = (char*)d_ws;
  u16*   feat_bf  = (u16*)(ws);                      // 25,624,576
  u16*   Wb_all   = (u16*)(ws + 25624576);           //    655,360
  u16*   G        = (u16*)(ws + 26279936);           // 102,498,304 (N_PAD*1024*2)
  int*   counts   = (int*)(ws + 128778240);          //    200,192
  int*   rowstart = (int*)(ws + 128978432);          //    200,448 (NSEG+1, padded)
  int*   cursor   = (int*)(ws + 129178880);          //    200,192
  int2*  ekv      = (int2*)(ws + 129379072);         //  6,400,000
  int*   blocksum = (int*)(ws + 135779072);          //        256

  // fused prep: feat->bf16, Wb transpose, zero counts
  prep_k<<<PREP_FEAT_BLOCKS + PREP_WT_BLOCKS + PREP_ZERO_BLOCKS, 256, 0, stream>>>(
      feat, weight, loop_w, feat_bf, Wb_all, counts);

  // CSR build over dst
  hist_k<<<(NUM_E + 255) / 256, 256, 0, stream>>>(dst, counts);
  scan1<<<NBLK, 1024, 0, stream>>>(counts, rowstart, blocksum);
  scan2<<<1, 512, 0, stream>>>(blocksum);
  scan3<<<NBLK + 1, 1024, 0, stream>>>(rowstart, blocksum, cursor);
  bucket_k<<<(NUM_E + 255) / 256, 256, 0, stream>>>(src, dst, et, norm, cursor, ekv);

  // aggregate into 4 base channels (1 wave/node; 8-wide scalar-edge groups)
  agg_G<<<N_NODES / 4, 256, 0, stream>>>(feat_bf, rowstart, ekv, w_comp, G);

  // one fused GEMM: K = 4 bases + self-loop; bias + relu fused
  fused_gemm<<<MTILES, 512, 0, stream>>>(G, feat_bf, Wb_all, h_bias, out);
}